// Round 21
// baseline (259.610 us; speedup 1.0000x reference)
//
#include <hip/hip_runtime.h>
#include <float.h>

#define NV 4096
#define OSTRIDE 451
#define NT 256
#define PK1OFF 6291456                 // float4[32768]  (131072 floats)
#define PK2OFF (6291456 + 131072)      // float4[16384]  (65536 floats)
#define PK3OFF (6291456 + 196608)      // float4[8192]   (32768 floats)
#define MARGIN 1e-3f
typedef unsigned long long u64;

// Wave-uniform top-8 list held as f32 BIT PATTERNS (u32) + idx, kept in
// SGPRs: d2 >= 0 so u32 compare == f32 compare. All inserts are uniform
// u32 ternaries -> SALU (s_cmp/s_cselect), freeing the VALU pipe.
struct Top8 {
    unsigned d0,d1,d2,d3,d4,d5,d6,d7;   // ascending
    int      i0,i1,i2,i3,i4,i5,i6,i7;
};

__device__ __forceinline__ void top8_init(Top8& t) {
    t.d0=t.d1=t.d2=t.d3=t.d4=t.d5=t.d6=t.d7=0x7F7FFFFFu;  // FLT_MAX bits
    t.i0=t.i1=t.i2=t.i3=t.i4=t.i5=t.i6=t.i7=0x7fffffff;
}

// sorted ascending insert (caller guarantees cd < t.d7); STRICT < placement:
// equal-key candidates go after existing entries, so ascending-idx processing
// reproduces top_k's stable tie semantics exactly. (PARTS=1: no merges.)
__device__ __forceinline__ void ins8s(Top8& t, unsigned cd, int cm) {
    bool b0 = cd < t.d0, b1 = cd < t.d1, b2 = cd < t.d2, b3 = cd < t.d3;
    bool b4 = cd < t.d4, b5 = cd < t.d5, b6 = cd < t.d6;
    t.d7 = b6 ? t.d6 : cd;                 t.i7 = b6 ? t.i6 : cm;
    t.d6 = b5 ? t.d5 : (b6 ? cd : t.d6);   t.i6 = b5 ? t.i5 : (b6 ? cm : t.i6);
    t.d5 = b4 ? t.d4 : (b5 ? cd : t.d5);   t.i5 = b4 ? t.i4 : (b5 ? cm : t.i5);
    t.d4 = b3 ? t.d3 : (b4 ? cd : t.d4);   t.i4 = b3 ? t.i3 : (b4 ? cm : t.i4);
    t.d3 = b2 ? t.d2 : (b3 ? cd : t.d3);   t.i3 = b2 ? t.i2 : (b3 ? cm : t.i3);
    t.d2 = b1 ? t.d1 : (b2 ? cd : t.d2);   t.i2 = b1 ? t.i1 : (b2 ? cm : t.i2);
    t.d1 = b0 ? t.d0 : (b1 ? cd : t.d1);   t.i1 = b0 ? t.i0 : (b1 ? cm : t.i1);
    t.d0 = b0 ? cd : t.d0;                 t.i0 = b0 ? cm : t.i0;
}

// wave-uniform event loop; ctz order = ascending lane = ascending idx within
// this mask (idx = ibase + lane). Refilter after each insert prunes storms.
// Only VALU per event: 1 readlane + 1 refilter v_cmp; rest is SALU.
__device__ __forceinline__ void handle_s(u64 mask, float dj, int ibase,
                                         Top8& t, float& Tf) {
    while (mask) {
        int l = __builtin_ctzll(mask);
        mask &= mask - 1;
        int cm = ibase + l;
        if (cm < 8) continue;                      // seed points already in list
        unsigned cd = (unsigned)__builtin_amdgcn_readlane(__float_as_uint(dj), l);
        if (cd < t.d7) {
            ins8s(t, cd, cm);
            Tf = __uint_as_float(t.d7);
            mask &= __ballot(dj < Tf);             // refilter vs tightened T
        }
    }
}

// weight: reference recomputes dist2 from vec = nbr - vert, numpy op order
// (round products, sequential add, no fma), w = 1/(1+dist2)
template<int M>
__device__ __forceinline__ float wcalc(const float* __restrict__ pc, int m,
                                       float vx, float vy, float vz) {
    float qx = pc[m], qy = pc[M+m], qz = pc[2*M+m];
    float dx = __fsub_rn(qx, vx), dy = __fsub_rn(qy, vy), dz = __fsub_rn(qz, vz);
    float dist2 = __fadd_rn(__fadd_rn(__fmul_rn(dx,dx), __fmul_rn(dy,dy)),
                            __fmul_rn(dz,dz));
    return __fdiv_rn(1.0f, __fadd_rn(1.0f, dist2));
}

// gate + exact-recheck + SALU handler for one 256-pt half-batch held in P.
// Identical numerics/order to R16: surrogate gate (strict <) vs Tg, exact
// direct-form d2 recheck (strict < vs T), in-order handler, j ascending.
__device__ __forceinline__ void gate256(
    const float4 (&P)[4], int ibase,
    const float (&c0)[2], const float (&c1)[2], const float (&c2)[2],
    const float (&v2m)[2], float (&Tg)[2], float (&T)[2],
    const float (&vx)[2], const float (&vy)[2], const float (&vz)[2],
    Top8& t0, Top8& t1)
{
    float s0[4], s1[4];
#pragma unroll
    for (int j = 0; j < 4; ++j) {
        s0[j] = __fmaf_rn(P[j].x, c0[0], __fmaf_rn(P[j].y, c1[0],
                __fmaf_rn(P[j].z, c2[0], P[j].w)));
        s1[j] = __fmaf_rn(P[j].x, c0[1], __fmaf_rn(P[j].y, c1[1],
                __fmaf_rn(P[j].z, c2[1], P[j].w)));
    }
    u64 g0[4], g1[4]; u64 any = 0;
#pragma unroll
    for (int j = 0; j < 4; ++j) {
        g0[j] = __ballot(s0[j] < Tg[0]);
        g1[j] = __ballot(s1[j] < Tg[1]);
        any |= g0[j] | g1[j];
    }
    if (any) {                                      // wave-uniform rare path
#pragma unroll
        for (int j = 0; j < 4; ++j) {               // j ascending = idx ascending
            if (g0[j]) {
                float dx = __fsub_rn(P[j].x, vx[0]);
                float dy = __fsub_rn(P[j].y, vy[0]);
                float dz = __fsub_rn(P[j].z, vz[0]);
                float d2x = __fmaf_rn(dz,dz,__fmaf_rn(dy,dy,__fmul_rn(dx,dx)));
                u64 em = __ballot(d2x < T[0]);      // exact, strict <
                if (em) {
                    handle_s(em, d2x, ibase + 64*j, t0, T[0]);
                    Tg[0] = __fsub_rn(T[0], v2m[0]);
                }
            }
        }
#pragma unroll
        for (int j = 0; j < 4; ++j) {
            if (g1[j]) {
                float dx = __fsub_rn(P[j].x, vx[1]);
                float dy = __fsub_rn(P[j].y, vy[1]);
                float dz = __fsub_rn(P[j].z, vz[1]);
                float d2x = __fmaf_rn(dz,dz,__fmaf_rn(dy,dy,__fmul_rn(dx,dx)));
                u64 em = __ballot(d2x < T[1]);
                if (em) {
                    handle_s(em, d2x, ibase + 64*j, t1, T[1]);
                    Tg[1] = __fsub_rn(T[1], v2m[1]);
                }
            }
        }
    }
}

// One wave owns 2 vertices, full scan of one stage (PARTS=1: minimal events,
// no merges, no LDS, no barriers). PK path: 512-pt loop iterations, two
// 256-pt half-batches in A/B register buffers with ROLE SWAP — no pipeline
// register copies (the 16 v_mov/batch of R16 are gone), depth-1 prefetch
// (A reloads under B's compute phase; R20 showed depth doesn't bind).
// Processing order A-half then B-half = globally idx-ascending -> exact
// tie semantics identical to R16. Selection distance = direct form
// (p-v).(p-v), ~500x tighter than the reference's cancellation form.
template<int M, int DF, int COFF, bool TR, bool PK>
__device__ __forceinline__ void stage2v(
    const float* __restrict__ verts,
    const float* __restrict__ pc,      // [3*M]
    const float* __restrict__ feat,    // [DF*M] (fallback gather)
    const float* __restrict__ featT,   // [M*DF] (transposed gather)
    const float4* __restrict__ pk,     // [M] packed (x,y,z,|p|^2) (PK only)
    float* __restrict__ out,
    int vbase, int lane)
{
    float vx[2], vy[2], vz[2];
#pragma unroll
    for (int u = 0; u < 2; ++u) {
        vx[u] = verts[(vbase+u)*3+0];
        vy[u] = verts[(vbase+u)*3+1];
        vz[u] = verts[(vbase+u)*3+2];
    }

    Top8 t0, t1;
    top8_init(t0); top8_init(t1);
#pragma unroll
    for (int q = 0; q < 8; ++q) {
        float sx = pc[q], sy = pc[M+q], sz = pc[2*M+q];
        {
            float dx=__fsub_rn(sx,vx[0]), dy=__fsub_rn(sy,vy[0]), dz=__fsub_rn(sz,vz[0]);
            float d = __fmaf_rn(dz,dz,__fmaf_rn(dy,dy,__fmul_rn(dx,dx)));
            unsigned cd = (unsigned)__builtin_amdgcn_readfirstlane(__float_as_uint(d));
            if (cd < t0.d7) ins8s(t0, cd, q);
        }
        {
            float dx=__fsub_rn(sx,vx[1]), dy=__fsub_rn(sy,vy[1]), dz=__fsub_rn(sz,vz[1]);
            float d = __fmaf_rn(dz,dz,__fmaf_rn(dy,dy,__fmul_rn(dx,dx)));
            unsigned cd = (unsigned)__builtin_amdgcn_readfirstlane(__float_as_uint(d));
            if (cd < t1.d7) ins8s(t1, cd, q);
        }
    }
    float T[2];
    T[0] = __uint_as_float(t0.d7);
    T[1] = __uint_as_float(t1.d7);

    // gate constants (PK): s = fma(px,c0, fma(py,c1, fma(pz,c2, pn)));
    // d2 = s + |v|^2 (+err<=~1e-4) -> gate s < T - (|v|^2 - MARGIN) is
    // strictly conservative. Rounding of c/v2m themselves is absorbed.
    float c0[2], c1[2], c2[2], v2m[2], Tg[2];
    if constexpr (PK) {
#pragma unroll
        for (int u = 0; u < 2; ++u) {
            c0[u] = __fmul_rn(-2.0f, vx[u]);
            c1[u] = __fmul_rn(-2.0f, vy[u]);
            c2[u] = __fmul_rn(-2.0f, vz[u]);
            float v2 = __fadd_rn(__fadd_rn(__fmul_rn(vx[u],vx[u]), __fmul_rn(vy[u],vy[u])),
                                 __fmul_rn(vz[u],vz[u]));
            v2m[u] = __fsub_rn(v2, MARGIN);
            Tg[u]  = __fsub_rn(T[u], v2m[u]);
        }
    }

    const float* __restrict__ px = pc;
    const float* __restrict__ py = pc + M;
    const float* __restrict__ pz = pc + 2*M;

    if constexpr (PK) {
        float4 A[4], B[4];
#pragma unroll
        for (int j = 0; j < 4; ++j) A[j] = pk[64*j + lane];
#pragma unroll
        for (int j = 0; j < 4; ++j) B[j] = pk[256 + 64*j + lane];

        for (int ob = 0; ob < M; ob += 512) {
            // half 1: points ob..ob+255 (in A); then reload A <- ob+512
            gate256(A, ob, c0,c1,c2, v2m, Tg, T, vx,vy,vz, t0, t1);
            int na = (ob + 512 < M) ? ob + 512 : 0;    // tail loads dead
#pragma unroll
            for (int j = 0; j < 4; ++j) A[j] = pk[na + 64*j + lane];
            // half 2: points ob+256..ob+511 (in B); then reload B <- ob+768
            gate256(B, ob + 256, c0,c1,c2, v2m, Tg, T, vx,vy,vz, t0, t1);
            int nb = (ob + 768 < M) ? ob + 768 : 0;
#pragma unroll
            for (int j = 0; j < 4; ++j) B[j] = pk[nb + 64*j + lane];
        }
    } else {
        float cx[4], cy[4], cz[4];
#pragma unroll
        for (int j = 0; j < 4; ++j) {
            cx[j] = px[64*j + lane]; cy[j] = py[64*j + lane]; cz[j] = pz[64*j + lane];
        }
        for (int ob = 0; ob < M; ob += 256) {
            int nb = (ob + 256 < M) ? ob + 256 : 0;
            float nx[4], ny[4], nz[4];
#pragma unroll
            for (int j = 0; j < 4; ++j) {
                nx[j] = px[nb + 64*j + lane];
                ny[j] = py[nb + 64*j + lane];
                nz[j] = pz[nb + 64*j + lane];
            }
            float d[2][4];
#pragma unroll
            for (int u = 0; u < 2; ++u)
#pragma unroll
                for (int j = 0; j < 4; ++j) {
                    float dx = __fsub_rn(cx[j], vx[u]);
                    float dy = __fsub_rn(cy[j], vy[u]);
                    float dz = __fsub_rn(cz[j], vz[u]);
                    d[u][j] = __fmaf_rn(dz,dz,__fmaf_rn(dy,dy,__fmul_rn(dx,dx)));
                }
            u64 msk[2][4]; u64 any = 0;
#pragma unroll
            for (int u = 0; u < 2; ++u)
#pragma unroll
                for (int j = 0; j < 4; ++j) {
                    msk[u][j] = __ballot(d[u][j] < T[u]);
                    any |= msk[u][j];
                }
            if (any) {
#pragma unroll
                for (int j = 0; j < 4; ++j)
                    handle_s(msk[0][j], d[0][j], ob + 64*j, t0, T[0]);
#pragma unroll
                for (int j = 0; j < 4; ++j)
                    handle_s(msk[1][j], d[1][j], ob + 64*j, t1, T[1]);
            }
#pragma unroll
            for (int j = 0; j < 4; ++j) { cx[j]=nx[j]; cy[j]=ny[j]; cz[j]=nz[j]; }
        }
    }

    int m8[2][8];
    m8[0][0]=t0.i0; m8[0][1]=t0.i1; m8[0][2]=t0.i2; m8[0][3]=t0.i3;
    m8[0][4]=t0.i4; m8[0][5]=t0.i5; m8[0][6]=t0.i6; m8[0][7]=t0.i7;
    m8[1][0]=t1.i0; m8[1][1]=t1.i1; m8[1][2]=t1.i2; m8[1][3]=t1.i3;
    m8[1][4]=t1.i4; m8[1][5]=t1.i5; m8[1][6]=t1.i6; m8[1][7]=t1.i7;
#pragma unroll
    for (int u = 0; u < 2; ++u) {
        float w8[8];
#pragma unroll
        for (int k = 0; k < 8; ++k)
            w8[k] = wcalc<M>(pc, m8[u][k], vx[u], vy[u], vz[u]);
        const int n = vbase + u;
        for (int f = lane; f < DF; f += 64) {
            float e[8];
#pragma unroll
            for (int k = 0; k < 8; ++k) {
                float fv = TR ? featT[m8[u][k]*DF + f] : feat[f*M + m8[u][k]];
                e[k] = __fmul_rn(w8[k], fv);
            }
            float s = __fadd_rn(__fadd_rn(__fadd_rn(e[0],e[1]), __fadd_rn(e[2],e[3])),
                                __fadd_rn(__fadd_rn(e[4],e[5]), __fadd_rn(e[6],e[7])));
            out[n*OSTRIDE + COFF + f] = __fmul_rn(0.125f, s);
        }
    }
}

// LDS-tiled transpose (blocks 0..1535): feat [Df,M] -> featT [M,Df], both
// sides coalesced. Blocks 1536..1759: fill packed float4 (x,y,z,|p|^2)
// arrays (bit-copies of pc values -> scan numerics unchanged).
__global__ __launch_bounds__(256)
void tr_kernel(const float* __restrict__ f1, const float* __restrict__ f2,
               const float* __restrict__ f3,
               const float* __restrict__ pc1, const float* __restrict__ pc2,
               const float* __restrict__ pc3, float* __restrict__ ws)
{
    int b = blockIdx.x;
    if (b >= 1536) {                                // pack fill (PK tier only)
        int g = (b - 1536)*256 + threadIdx.x;       // 0..57343
        float x, y, z; float4* dst;
        if (g < 32768)      { x=pc1[g];      y=pc1[32768+g];  z=pc1[65536+g];  dst=(float4*)(ws+PK1OFF)+g; }
        else if (g < 49152) { int m=g-32768; x=pc2[m]; y=pc2[16384+m]; z=pc2[32768+m]; dst=(float4*)(ws+PK2OFF)+m; }
        else                { int m=g-49152; x=pc3[m]; y=pc3[8192+m];  z=pc3[16384+m]; dst=(float4*)(ws+PK3OFF)+m; }
        float pn = __fmaf_rn(z,z,__fmaf_rn(y,y,__fmul_rn(x,x)));
        *dst = make_float4(x, y, z, pn);
        return;
    }
    __shared__ float s[64][65];
    const float* src; float* dst; int M, DF, tm, tf;
    if (b < 512)       { src = f1; dst = ws;           M = 32768; DF = 64;  tm = b & 511;        tf = b >> 9; }
    else if (b < 1024) { src = f2; dst = ws + 2097152; M = 16384; DF = 128; tm = (b-512) & 255;  tf = (b-512) >> 8; }
    else               { src = f3; dst = ws + 4194304; M = 8192;  DF = 256; tm = (b-1024) & 127; tf = (b-1024) >> 7; }
    const int mb = tm*64, fb = tf*64;
    const int tid = threadIdx.x;
    const int a0 = tid & 63, a1 = tid >> 6;
#pragma unroll
    for (int i = 0; i < 16; ++i) {
        int ff = a1 + i*4;
        s[ff][a0] = src[(fb+ff)*M + mb + a0];
    }
    __syncthreads();
#pragma unroll
    for (int i = 0; i < 16; ++i) {
        int mm2 = a1 + i*4;
        dst[(mb+mm2)*DF + fb + a0] = s[a0][mm2];
    }
}

// Grid (R13/R16 winner, unchanged): 1537 blocks x 4 waves, U=2 verts/wave,
// one stage per block: b<512 s1, b<1024 s2, b<1536 s3, b=1536 coord-copy.
// 6144 scan waves = one residency round at 6 blocks/CU. Same-stage blocks
// scan start-aligned (R18: stagger regresses 2x — aligned L2 multicast wins).
template<bool TR, bool PK>
__global__ __launch_bounds__(NT, 6)
void gp_kernel(const float* __restrict__ verts,
               const float* __restrict__ pc1, const float* __restrict__ f1,
               const float* __restrict__ pc2, const float* __restrict__ f2,
               const float* __restrict__ pc3, const float* __restrict__ f3,
               const float* __restrict__ ws,
               float* __restrict__ out)
{
    int b = blockIdx.x;
    if (b < 1536) {
        const int lane = threadIdx.x & 63;
        const int wv   = threadIdx.x >> 6;
        if (b < 512) {
            stage2v<32768,  64,   3, TR, PK>(verts, pc1, f1, ws,
                (const float4*)(ws+PK1OFF), out, (b*4 + wv)*2, lane);
        } else if (b < 1024) {
            stage2v<16384, 128,  67, TR, PK>(verts, pc2, f2, ws + 2097152,
                (const float4*)(ws+PK2OFF), out, ((b-512)*4 + wv)*2, lane);
        } else {
            stage2v< 8192, 256, 195, TR, PK>(verts, pc3, f3, ws + 4194304,
                (const float4*)(ws+PK3OFF), out, ((b-1024)*4 + wv)*2, lane);
        }
    } else {
        for (int i = threadIdx.x; i < NV*3; i += NT)
            out[(i/3)*OSTRIDE + (i % 3)] = verts[i];
    }
}

extern "C" void kernel_launch(void* const* d_in, const int* in_sizes, int n_in,
                              void* d_out, int out_size, void* d_ws, size_t ws_size,
                              hipStream_t stream) {
    const float* verts = (const float*)d_in[0];
    // d_in[1] = pc0_coords: unused (reference discards stage 0)
    const float* pc1 = (const float*)d_in[2];
    const float* f1  = (const float*)d_in[3];
    const float* pc2 = (const float*)d_in[4];
    const float* f2  = (const float*)d_in[5];
    const float* pc3 = (const float*)d_in[6];
    const float* f3  = (const float*)d_in[7];
    float* out = (float*)d_out;
    float* ws  = (float*)d_ws;

    const size_t need_tr = 6291456ull * 4ull;
    const size_t need_pk = (6291456ull + 229376ull) * 4ull;
    if (ws_size >= need_pk) {
        tr_kernel<<<1760, 256, 0, stream>>>(f1, f2, f3, pc1, pc2, pc3, ws);
        gp_kernel<true, true><<<1537, NT, 0, stream>>>(verts, pc1, f1, pc2, f2, pc3, f3, ws, out);
    } else if (ws_size >= need_tr) {
        tr_kernel<<<1536, 256, 0, stream>>>(f1, f2, f3, pc1, pc2, pc3, ws);
        gp_kernel<true, false><<<1537, NT, 0, stream>>>(verts, pc1, f1, pc2, f2, pc3, f3, ws, out);
    } else {
        gp_kernel<false, false><<<1537, NT, 0, stream>>>(verts, pc1, f1, pc2, f2, pc3, f3, ws, out);
    }
}

// Round 22
// 114.913 us; speedup vs baseline: 2.2592x; 2.2592x over previous
//
#include <hip/hip_runtime.h>
#include <float.h>

#define NV 4096
#define OSTRIDE 451
#define NT 256
#define PK1OFF 6291456                 // float4[32768]  (131072 floats)
#define PK2OFF (6291456 + 131072)      // float4[16384]  (65536 floats)
#define PK3OFF (6291456 + 196608)      // float4[8192]   (32768 floats)
#define MARGIN 1e-3f
typedef unsigned long long u64;

// Wave-uniform top-8 list held as f32 BIT PATTERNS (u32) + idx, kept in
// SGPRs: d2 >= 0 so u32 compare == f32 compare. All inserts are uniform
// u32 ternaries -> SALU (s_cmp/s_cselect), freeing the VALU pipe.
struct Top8 {
    unsigned d0,d1,d2,d3,d4,d5,d6,d7;   // ascending
    int      i0,i1,i2,i3,i4,i5,i6,i7;
};

__device__ __forceinline__ void top8_init(Top8& t) {
    t.d0=t.d1=t.d2=t.d3=t.d4=t.d5=t.d6=t.d7=0x7F7FFFFFu;  // FLT_MAX bits
    t.i0=t.i1=t.i2=t.i3=t.i4=t.i5=t.i6=t.i7=0x7fffffff;
}

// sorted ascending insert (caller guarantees cd < t.d7); STRICT < placement:
// equal-key candidates go after existing entries, so ascending-idx processing
// reproduces top_k's stable tie semantics exactly. (PARTS=1: no merges.)
__device__ __forceinline__ void ins8s(Top8& t, unsigned cd, int cm) {
    bool b0 = cd < t.d0, b1 = cd < t.d1, b2 = cd < t.d2, b3 = cd < t.d3;
    bool b4 = cd < t.d4, b5 = cd < t.d5, b6 = cd < t.d6;
    t.d7 = b6 ? t.d6 : cd;                 t.i7 = b6 ? t.i6 : cm;
    t.d6 = b5 ? t.d5 : (b6 ? cd : t.d6);   t.i6 = b5 ? t.i5 : (b6 ? cm : t.i6);
    t.d5 = b4 ? t.d4 : (b5 ? cd : t.d5);   t.i5 = b4 ? t.i4 : (b5 ? cm : t.i5);
    t.d4 = b3 ? t.d3 : (b4 ? cd : t.d4);   t.i4 = b3 ? t.i3 : (b4 ? cm : t.i4);
    t.d3 = b2 ? t.d2 : (b3 ? cd : t.d3);   t.i3 = b2 ? t.i2 : (b3 ? cm : t.i3);
    t.d2 = b1 ? t.d1 : (b2 ? cd : t.d2);   t.i2 = b1 ? t.i1 : (b2 ? cm : t.i2);
    t.d1 = b0 ? t.d0 : (b1 ? cd : t.d1);   t.i1 = b0 ? t.i0 : (b1 ? cm : t.i1);
    t.d0 = b0 ? cd : t.d0;                 t.i0 = b0 ? cm : t.i0;
}

// wave-uniform event loop; ctz order = ascending lane = ascending idx within
// this mask (idx = ibase + lane). Refilter after each insert prunes storms.
// Only VALU per event: 1 readlane + 1 refilter v_cmp; rest is SALU.
__device__ __forceinline__ void handle_s(u64 mask, float dj, int ibase,
                                         Top8& t, float& Tf) {
    while (mask) {
        int l = __builtin_ctzll(mask);
        mask &= mask - 1;
        int cm = ibase + l;
        if (cm < 8) continue;                      // seed points already in list
        unsigned cd = (unsigned)__builtin_amdgcn_readlane(__float_as_uint(dj), l);
        if (cd < t.d7) {
            ins8s(t, cd, cm);
            Tf = __uint_as_float(t.d7);
            mask &= __ballot(dj < Tf);             // refilter vs tightened T
        }
    }
}

// weight: reference recomputes dist2 from vec = nbr - vert, numpy op order
// (round products, sequential add, no fma), w = 1/(1+dist2)
template<int M>
__device__ __forceinline__ float wcalc(const float* __restrict__ pc, int m,
                                       float vx, float vy, float vz) {
    float qx = pc[m], qy = pc[M+m], qz = pc[2*M+m];
    float dx = __fsub_rn(qx, vx), dy = __fsub_rn(qy, vy), dz = __fsub_rn(qz, vz);
    float dist2 = __fadd_rn(__fadd_rn(__fmul_rn(dx,dx), __fmul_rn(dy,dy)),
                            __fmul_rn(dz,dz));
    return __fdiv_rn(1.0f, __fadd_rn(1.0f, dist2));
}

// One wave owns 2 vertices, full scan of one stage (PARTS=1: minimal events,
// no merges, no LDS, no barriers). 256-pt batches, lane-strided (lane l ->
// idx ob+64j+l, j-major processing = globally idx-ascending -> exact ties).
// PK path: one float4 (x,y,z,|p|^2) load per lane per j -> 4 VMEM/batch
// (vs 16 scalar); gate with monotone surrogate s = pn - 2 p.v (3 fma/pair)
// against conservative threshold T - (|v|^2 - MARGIN); on hit, recompute the
// exact direct-form d2 (bit-identical values: pack is a bit-copy of pc) and
// re-ballot against T before the SALU handler -> selection identical.
template<int M, int DF, int COFF, bool TR, bool PK>
__device__ __forceinline__ void stage2v(
    const float* __restrict__ verts,
    const float* __restrict__ pc,      // [3*M]
    const float* __restrict__ feat,    // [DF*M] (fallback gather)
    const float* __restrict__ featT,   // [M*DF] (transposed gather)
    const float4* __restrict__ pk,     // [M] packed (x,y,z,|p|^2) (PK only)
    float* __restrict__ out,
    int vbase, int lane)
{
    float vx[2], vy[2], vz[2];
#pragma unroll
    for (int u = 0; u < 2; ++u) {
        vx[u] = verts[(vbase+u)*3+0];
        vy[u] = verts[(vbase+u)*3+1];
        vz[u] = verts[(vbase+u)*3+2];
    }

    Top8 t0, t1;
    top8_init(t0); top8_init(t1);
#pragma unroll
    for (int q = 0; q < 8; ++q) {
        float sx = pc[q], sy = pc[M+q], sz = pc[2*M+q];
        {
            float dx=__fsub_rn(sx,vx[0]), dy=__fsub_rn(sy,vy[0]), dz=__fsub_rn(sz,vz[0]);
            float d = __fmaf_rn(dz,dz,__fmaf_rn(dy,dy,__fmul_rn(dx,dx)));
            unsigned cd = (unsigned)__builtin_amdgcn_readfirstlane(__float_as_uint(d));
            if (cd < t0.d7) ins8s(t0, cd, q);
        }
        {
            float dx=__fsub_rn(sx,vx[1]), dy=__fsub_rn(sy,vy[1]), dz=__fsub_rn(sz,vz[1]);
            float d = __fmaf_rn(dz,dz,__fmaf_rn(dy,dy,__fmul_rn(dx,dx)));
            unsigned cd = (unsigned)__builtin_amdgcn_readfirstlane(__float_as_uint(d));
            if (cd < t1.d7) ins8s(t1, cd, q);
        }
    }
    float T[2];
    T[0] = __uint_as_float(t0.d7);
    T[1] = __uint_as_float(t1.d7);

    // gate constants (PK): s = fma(px,c0, fma(py,c1, fma(pz,c2, pn)));
    // d2 = s + |v|^2 (+err<=~1e-4) -> gate s < T - (|v|^2 - MARGIN) is
    // strictly conservative. Rounding of c/v2m themselves is absorbed.
    float c0[2], c1[2], c2[2], v2m[2], Tg[2];
    if constexpr (PK) {
#pragma unroll
        for (int u = 0; u < 2; ++u) {
            c0[u] = __fmul_rn(-2.0f, vx[u]);
            c1[u] = __fmul_rn(-2.0f, vy[u]);
            c2[u] = __fmul_rn(-2.0f, vz[u]);
            float v2 = __fadd_rn(__fadd_rn(__fmul_rn(vx[u],vx[u]), __fmul_rn(vy[u],vy[u])),
                                 __fmul_rn(vz[u],vz[u]));
            v2m[u] = __fsub_rn(v2, MARGIN);
            Tg[u]  = __fsub_rn(T[u], v2m[u]);
        }
    }

    const float* __restrict__ px = pc;
    const float* __restrict__ py = pc + M;
    const float* __restrict__ pz = pc + 2*M;

    if constexpr (PK) {
        float4 cp[4];
#pragma unroll
        for (int j = 0; j < 4; ++j) cp[j] = pk[64*j + lane];

        for (int ob = 0; ob < M; ob += 256) {
            int nb = (ob + 256 < M) ? ob + 256 : 0;     // last prefetch dead
            float4 np[4];
#pragma unroll
            for (int j = 0; j < 4; ++j) np[j] = pk[nb + 64*j + lane];
            float s0[4], s1[4];
#pragma unroll
            for (int j = 0; j < 4; ++j) {
                s0[j] = __fmaf_rn(cp[j].x, c0[0], __fmaf_rn(cp[j].y, c1[0],
                        __fmaf_rn(cp[j].z, c2[0], cp[j].w)));
                s1[j] = __fmaf_rn(cp[j].x, c0[1], __fmaf_rn(cp[j].y, c1[1],
                        __fmaf_rn(cp[j].z, c2[1], cp[j].w)));
            }
            u64 g0[4], g1[4]; u64 any = 0;
#pragma unroll
            for (int j = 0; j < 4; ++j) {
                g0[j] = __ballot(s0[j] < Tg[0]);
                g1[j] = __ballot(s1[j] < Tg[1]);
                any |= g0[j] | g1[j];
            }
            if (any) {                               // wave-uniform rare path
#pragma unroll
                for (int j = 0; j < 4; ++j) {        // j ascending = idx ascending
                    if (g0[j]) {
                        float dx = __fsub_rn(cp[j].x, vx[0]);
                        float dy = __fsub_rn(cp[j].y, vy[0]);
                        float dz = __fsub_rn(cp[j].z, vz[0]);
                        float d2x = __fmaf_rn(dz,dz,__fmaf_rn(dy,dy,__fmul_rn(dx,dx)));
                        u64 em = __ballot(d2x < T[0]);   // exact, strict <
                        if (em) {
                            handle_s(em, d2x, ob + 64*j, t0, T[0]);
                            Tg[0] = __fsub_rn(T[0], v2m[0]);
                        }
                    }
                }
#pragma unroll
                for (int j = 0; j < 4; ++j) {
                    if (g1[j]) {
                        float dx = __fsub_rn(cp[j].x, vx[1]);
                        float dy = __fsub_rn(cp[j].y, vy[1]);
                        float dz = __fsub_rn(cp[j].z, vz[1]);
                        float d2x = __fmaf_rn(dz,dz,__fmaf_rn(dy,dy,__fmul_rn(dx,dx)));
                        u64 em = __ballot(d2x < T[1]);
                        if (em) {
                            handle_s(em, d2x, ob + 64*j, t1, T[1]);
                            Tg[1] = __fsub_rn(T[1], v2m[1]);
                        }
                    }
                }
            }
#pragma unroll
            for (int j = 0; j < 4; ++j) cp[j] = np[j];
        }
    } else {
        float cx[4], cy[4], cz[4];
#pragma unroll
        for (int j = 0; j < 4; ++j) {
            cx[j] = px[64*j + lane]; cy[j] = py[64*j + lane]; cz[j] = pz[64*j + lane];
        }
        for (int ob = 0; ob < M; ob += 256) {
            int nb = (ob + 256 < M) ? ob + 256 : 0;
            float nx[4], ny[4], nz[4];
#pragma unroll
            for (int j = 0; j < 4; ++j) {
                nx[j] = px[nb + 64*j + lane];
                ny[j] = py[nb + 64*j + lane];
                nz[j] = pz[nb + 64*j + lane];
            }
            float d[2][4];
#pragma unroll
            for (int u = 0; u < 2; ++u)
#pragma unroll
                for (int j = 0; j < 4; ++j) {
                    float dx = __fsub_rn(cx[j], vx[u]);
                    float dy = __fsub_rn(cy[j], vy[u]);
                    float dz = __fsub_rn(cz[j], vz[u]);
                    d[u][j] = __fmaf_rn(dz,dz,__fmaf_rn(dy,dy,__fmul_rn(dx,dx)));
                }
            u64 msk[2][4]; u64 any = 0;
#pragma unroll
            for (int u = 0; u < 2; ++u)
#pragma unroll
                for (int j = 0; j < 4; ++j) {
                    msk[u][j] = __ballot(d[u][j] < T[u]);
                    any |= msk[u][j];
                }
            if (any) {
#pragma unroll
                for (int j = 0; j < 4; ++j)
                    handle_s(msk[0][j], d[0][j], ob + 64*j, t0, T[0]);
#pragma unroll
                for (int j = 0; j < 4; ++j)
                    handle_s(msk[1][j], d[1][j], ob + 64*j, t1, T[1]);
            }
#pragma unroll
            for (int j = 0; j < 4; ++j) { cx[j]=nx[j]; cy[j]=ny[j]; cz[j]=nz[j]; }
        }
    }

    int m8[2][8];
    m8[0][0]=t0.i0; m8[0][1]=t0.i1; m8[0][2]=t0.i2; m8[0][3]=t0.i3;
    m8[0][4]=t0.i4; m8[0][5]=t0.i5; m8[0][6]=t0.i6; m8[0][7]=t0.i7;
    m8[1][0]=t1.i0; m8[1][1]=t1.i1; m8[1][2]=t1.i2; m8[1][3]=t1.i3;
    m8[1][4]=t1.i4; m8[1][5]=t1.i5; m8[1][6]=t1.i6; m8[1][7]=t1.i7;
#pragma unroll
    for (int u = 0; u < 2; ++u) {
        float w8[8];
#pragma unroll
        for (int k = 0; k < 8; ++k)
            w8[k] = wcalc<M>(pc, m8[u][k], vx[u], vy[u], vz[u]);
        const int n = vbase + u;
        for (int f = lane; f < DF; f += 64) {
            float e[8];
#pragma unroll
            for (int k = 0; k < 8; ++k) {
                float fv = TR ? featT[m8[u][k]*DF + f] : feat[f*M + m8[u][k]];
                e[k] = __fmul_rn(w8[k], fv);
            }
            float s = __fadd_rn(__fadd_rn(__fadd_rn(e[0],e[1]), __fadd_rn(e[2],e[3])),
                                __fadd_rn(__fadd_rn(e[4],e[5]), __fadd_rn(e[6],e[7])));
            out[n*OSTRIDE + COFF + f] = __fmul_rn(0.125f, s);
        }
    }
}

// LDS-tiled transpose (blocks 0..1535): feat [Df,M] -> featT [M,Df], both
// sides coalesced. Blocks 1536..1759: fill packed float4 (x,y,z,|p|^2)
// arrays (bit-copies of pc values -> scan numerics unchanged).
__global__ __launch_bounds__(256)
void tr_kernel(const float* __restrict__ f1, const float* __restrict__ f2,
               const float* __restrict__ f3,
               const float* __restrict__ pc1, const float* __restrict__ pc2,
               const float* __restrict__ pc3, float* __restrict__ ws)
{
    int b = blockIdx.x;
    if (b >= 1536) {                                // pack fill (PK tier only)
        int g = (b - 1536)*256 + threadIdx.x;       // 0..57343
        float x, y, z; float4* dst;
        if (g < 32768)      { x=pc1[g];      y=pc1[32768+g];  z=pc1[65536+g];  dst=(float4*)(ws+PK1OFF)+g; }
        else if (g < 49152) { int m=g-32768; x=pc2[m]; y=pc2[16384+m]; z=pc2[32768+m]; dst=(float4*)(ws+PK2OFF)+m; }
        else                { int m=g-49152; x=pc3[m]; y=pc3[8192+m];  z=pc3[16384+m]; dst=(float4*)(ws+PK3OFF)+m; }
        float pn = __fmaf_rn(z,z,__fmaf_rn(y,y,__fmul_rn(x,x)));
        *dst = make_float4(x, y, z, pn);
        return;
    }
    __shared__ float s[64][65];
    const float* src; float* dst; int M, DF, tm, tf;
    if (b < 512)       { src = f1; dst = ws;           M = 32768; DF = 64;  tm = b & 511;        tf = b >> 9; }
    else if (b < 1024) { src = f2; dst = ws + 2097152; M = 16384; DF = 128; tm = (b-512) & 255;  tf = (b-512) >> 8; }
    else               { src = f3; dst = ws + 4194304; M = 8192;  DF = 256; tm = (b-1024) & 127; tf = (b-1024) >> 7; }
    const int mb = tm*64, fb = tf*64;
    const int tid = threadIdx.x;
    const int a0 = tid & 63, a1 = tid >> 6;
#pragma unroll
    for (int i = 0; i < 16; ++i) {
        int ff = a1 + i*4;
        s[ff][a0] = src[(fb+ff)*M + mb + a0];
    }
    __syncthreads();
#pragma unroll
    for (int i = 0; i < 16; ++i) {
        int mm2 = a1 + i*4;
        dst[(mb+mm2)*DF + fb + a0] = s[a0][mm2];
    }
}

// Grid (R13/R15 winner, unchanged): 1537 blocks x 4 waves, U=2 verts/wave,
// one stage per block: b<512 s1, b<1024 s2, b<1536 s3, b=1536 coord-copy.
// 6144 scan waves = one residency round at 6 blocks/CU.
template<bool TR, bool PK>
__global__ __launch_bounds__(NT, 6)
void gp_kernel(const float* __restrict__ verts,
               const float* __restrict__ pc1, const float* __restrict__ f1,
               const float* __restrict__ pc2, const float* __restrict__ f2,
               const float* __restrict__ pc3, const float* __restrict__ f3,
               const float* __restrict__ ws,
               float* __restrict__ out)
{
    int b = blockIdx.x;
    if (b < 1536) {
        const int lane = threadIdx.x & 63;
        const int wv   = threadIdx.x >> 6;
        if (b < 512) {
            stage2v<32768,  64,   3, TR, PK>(verts, pc1, f1, ws,
                (const float4*)(ws+PK1OFF), out, (b*4 + wv)*2, lane);
        } else if (b < 1024) {
            stage2v<16384, 128,  67, TR, PK>(verts, pc2, f2, ws + 2097152,
                (const float4*)(ws+PK2OFF), out, ((b-512)*4 + wv)*2, lane);
        } else {
            stage2v< 8192, 256, 195, TR, PK>(verts, pc3, f3, ws + 4194304,
                (const float4*)(ws+PK3OFF), out, ((b-1024)*4 + wv)*2, lane);
        }
    } else {
        for (int i = threadIdx.x; i < NV*3; i += NT)
            out[(i/3)*OSTRIDE + (i % 3)] = verts[i];
    }
}

extern "C" void kernel_launch(void* const* d_in, const int* in_sizes, int n_in,
                              void* d_out, int out_size, void* d_ws, size_t ws_size,
                              hipStream_t stream) {
    const float* verts = (const float*)d_in[0];
    // d_in[1] = pc0_coords: unused (reference discards stage 0)
    const float* pc1 = (const float*)d_in[2];
    const float* f1  = (const float*)d_in[3];
    const float* pc2 = (const float*)d_in[4];
    const float* f2  = (const float*)d_in[5];
    const float* pc3 = (const float*)d_in[6];
    const float* f3  = (const float*)d_in[7];
    float* out = (float*)d_out;
    float* ws  = (float*)d_ws;

    const size_t need_tr = 6291456ull * 4ull;
    const size_t need_pk = (6291456ull + 229376ull) * 4ull;
    if (ws_size >= need_pk) {
        tr_kernel<<<1760, 256, 0, stream>>>(f1, f2, f3, pc1, pc2, pc3, ws);
        gp_kernel<true, true><<<1537, NT, 0, stream>>>(verts, pc1, f1, pc2, f2, pc3, f3, ws, out);
    } else if (ws_size >= need_tr) {
        tr_kernel<<<1536, 256, 0, stream>>>(f1, f2, f3, pc1, pc2, pc3, ws);
        gp_kernel<true, false><<<1537, NT, 0, stream>>>(verts, pc1, f1, pc2, f2, pc3, f3, ws, out);
    } else {
        gp_kernel<false, false><<<1537, NT, 0, stream>>>(verts, pc1, f1, pc2, f2, pc3, f3, ws, out);
    }
}